// Round 14
// baseline (390.878 us; speedup 1.0000x reference)
//
#include <hip/hip_runtime.h>
#include <stdint.h>

// Problem constants (fixed by the reference)
#define Bc 4
#define Sc 2048
#define Dc 768
#define Kc 8192
#define NSc 2
#define Mc (Bc*Sc)                      // 8192 tokens
#define EMB_ELEMS ((size_t)Mc*NSc*Dc)   // emb output floats; indices follow

typedef __attribute__((ext_vector_type(8))) __bf16 bf16x8;
typedef __attribute__((ext_vector_type(4))) float f32x4;
typedef __attribute__((ext_vector_type(4))) unsigned short u16x4;
typedef __attribute__((ext_vector_type(8))) unsigned short u16x8;

__device__ __forceinline__ unsigned short f2bf(float f){
  unsigned int u = __float_as_uint(f);
  u += 0x7FFFu + ((u >> 16) & 1u);       // round-to-nearest-even
  return (unsigned short)(u >> 16);
}
__device__ __forceinline__ float bf2f(unsigned short h){
  return __uint_as_float(((unsigned int)h) << 16);
}

// ---------------- K0: convert x,w f32 -> bf16 (into ws) ----------------
__global__ __launch_bounds__(256) void k_convert(const float4* __restrict__ x,
                                                 const float4* __restrict__ w,
                                                 u16x4* __restrict__ xb,
                                                 u16x4* __restrict__ wb){
  int i = blockIdx.x * 256 + threadIdx.x;
  float4 v = x[i];
  u16x4 o;
  o.x = f2bf(v.x); o.y = f2bf(v.y); o.z = f2bf(v.z); o.w = f2bf(v.w);
  xb[i] = o;
  v = w[i];
  o.x = f2bf(v.x); o.y = f2bf(v.y); o.z = f2bf(v.z); o.w = f2bf(v.w);
  wb[i] = o;
}

// ---------------- K1: r13 GEMM + per-(token, 64-col slice) max_l stats -------
// stats: bf16 max_l at (ushort*)out_emb + token*3072 + slice (256 B per token,
// inside the out_emb row; select reads them before overwriting with the gather).
#define BM 128
#define BN 128
#define BK 32

__global__ __launch_bounds__(512, 2) void k_gemm(const unsigned short* __restrict__ xb,
                                                 const unsigned short* __restrict__ wb,
                                                 unsigned short* stash,
                                                 unsigned short* statsb){
  __shared__ __align__(16) unsigned char lds[131072];   // 2 x (A 32K | B 32K)

  const int tid  = threadIdx.x;
  const int lane = tid & 63;
  const int wid  = tid >> 6;             // 8 waves
  const int wr   = wid >> 2;             // M half (0..1)
  const int wc   = wid & 3;              // N quarter (0..3)
  const int fr   = lane & 15;
  const int fq   = lane >> 4;

  // column-ownership XCD swizzle (r12, bijective)
  const int bid = (int)blockIdx.x;
  const int xcd = bid & 7;
  const int ii  = bid >> 3;              // 0..127
  const int bm0 = (ii >> 2) * 256;       // row 0..31 (advances per round)
  const int bn0 = (xcd * 4 + (ii & 3)) * 256;   // col: 4 panels owned per XCD

  float* zbase = (float*)stash;          // out_ind base (row t = 16384 floats)
  const int zpan = bn0 >> 8;             // 0..31: this block's zero partition

  f32x4 acc[8][4] = {};

  const int rin   = tid >> 3;                 // row within unit (0..63)
  const int kblkp = (tid & 7) ^ (rin & 7);    // inverse-swizzled k-block
  const unsigned short* gsrc[8];
  unsigned dstoff[8];
  #pragma unroll
  for (int s = 0; s < 8; ++s) {
    const int isA = s >> 2;
    const int q   = s & 3;
    const int r64 = isA ? (((q & 1) << 1) | (q >> 1)) : q;   // A order 0,2,1,3
    const int grow = (isA ? bm0 : bn0) + r64 * 64 + rin;
    gsrc[s]   = (isA ? xb : wb) + (size_t)grow * Dc + kblkp * 8;
    dstoff[s] = (isA ? 0u : 32768u) + (unsigned)r64 * 8192u + (unsigned)wid * 1024u;
  }

#define ISSUE(s_, bo_) __builtin_amdgcn_global_load_lds( \
    (const __attribute__((address_space(1))) void*)gsrc[s_], \
    (__attribute__((address_space(3))) void*)&lds[(bo_) + dstoff[s_]], 16, 0, 0)

#define ZSTORE(u_) do { \
    const unsigned g_ = (unsigned)(t*4 + (u_))*512u + (unsigned)tid; \
    const unsigned tl_ = g_ / 96u, j4_ = g_ - tl_*96u; \
    const f32x4 z_ = {0.f, 0.f, 0.f, 0.f}; \
    __builtin_nontemporal_store(z_, (f32x4*)(zbase + \
        (size_t)(bm0 + tl_)*16384 + 4096 + zpan*384 + j4_*4)); \
  } while (0)

  // prologue: tile 0 -> buf0
  #pragma unroll
  for (int s = 0; s < 8; ++s) ISSUE(s, 0u);
  #pragma unroll
  for (int s = 0; s < 8; ++s) gsrc[s] += 64;             // point at tile 1

  unsigned bufR = 0u, bufW = 65536u;
  const unsigned aRow = (unsigned)(wr*128 + fr) * 128u;            // A row byte
  const unsigned bRow = (unsigned)(wc*64  + fr) * 128u + 32768u;   // B row byte
  const unsigned sl0  = (unsigned)((fq       ) ^ (fr & 7)) * 16u;  // k-step 0 slot
  const unsigned sl1  = (unsigned)((fq + 4   ) ^ (fr & 7)) * 16u;  // k-step 1 slot

  for (int t = 0; t < 12; ++t) {
    const bool more = (t < 11);
    bf16x8 a[4], b0[4], b1[4];

    // ---------------- ph0 ----------------
    if (t == 0) asm volatile("s_waitcnt vmcnt(2)" ::: "memory");
    else        asm volatile("s_waitcnt vmcnt(6)" ::: "memory");
    __builtin_amdgcn_s_barrier();
    asm volatile("" ::: "memory");
    if (more) { ISSUE(0, bufW); ISSUE(1, bufW); }
    #pragma unroll
    for (int n = 0; n < 4; ++n) b0[n] = *(const bf16x8*)&lds[bufR + bRow + (unsigned)n*2048u + sl0];
    #pragma unroll
    for (int m = 0; m < 4; ++m) a[m]  = *(const bf16x8*)&lds[bufR + aRow + (unsigned)m*2048u + sl0];
    __builtin_amdgcn_s_setprio(1);
    #pragma unroll
    for (int m = 0; m < 4; ++m)
      #pragma unroll
      for (int n = 0; n < 4; ++n)
        acc[m][n] = __builtin_amdgcn_mfma_f32_16x16x32_bf16(a[m], b0[n], acc[m][n], 0, 0, 0);
    __builtin_amdgcn_s_setprio(0);

    // ---------------- ph1 ----------------
    if (!more)       asm volatile("s_waitcnt vmcnt(0)" ::: "memory");
    else if (t == 0) asm volatile("s_waitcnt vmcnt(2)" ::: "memory");
    else             asm volatile("s_waitcnt vmcnt(4)" ::: "memory");
    __builtin_amdgcn_s_barrier();
    asm volatile("" ::: "memory");
    if (more) { ISSUE(2, bufW); ISSUE(3, bufW); }
    #pragma unroll
    for (int m = 0; m < 4; ++m) a[m] = *(const bf16x8*)&lds[bufR + aRow + 8192u + (unsigned)m*2048u + sl0];
    __builtin_amdgcn_s_setprio(1);
    #pragma unroll
    for (int m = 0; m < 4; ++m)
      #pragma unroll
      for (int n = 0; n < 4; ++n)
        acc[4+m][n] = __builtin_amdgcn_mfma_f32_16x16x32_bf16(a[m], b0[n], acc[4+m][n], 0, 0, 0);
    __builtin_amdgcn_s_setprio(0);

    // ---------------- ph2 (waitless) ----------------
    if (more) { ISSUE(4, bufW); ISSUE(5, bufW); }
    asm volatile("" ::: "memory");
    ZSTORE(0); ZSTORE(1);
    asm volatile("" ::: "memory");
    #pragma unroll
    for (int n = 0; n < 4; ++n) b1[n] = *(const bf16x8*)&lds[bufR + bRow + (unsigned)n*2048u + sl1];
    #pragma unroll
    for (int m = 0; m < 4; ++m) a[m]  = *(const bf16x8*)&lds[bufR + aRow + (unsigned)m*2048u + sl1];
    __builtin_amdgcn_s_setprio(1);
    #pragma unroll
    for (int m = 0; m < 4; ++m)
      #pragma unroll
      for (int n = 0; n < 4; ++n)
        acc[m][n] = __builtin_amdgcn_mfma_f32_16x16x32_bf16(a[m], b1[n], acc[m][n], 0, 0, 0);
    __builtin_amdgcn_s_setprio(0);

    // ---------------- ph3 (waitless) ----------------
    if (more) { ISSUE(6, bufW); ISSUE(7, bufW); }
    asm volatile("" ::: "memory");
    ZSTORE(2); ZSTORE(3);
    asm volatile("" ::: "memory");
    #pragma unroll
    for (int m = 0; m < 4; ++m) a[m] = *(const bf16x8*)&lds[bufR + aRow + 8192u + (unsigned)m*2048u + sl1];
    __builtin_amdgcn_s_setprio(1);
    #pragma unroll
    for (int m = 0; m < 4; ++m)
      #pragma unroll
      for (int n = 0; n < 4; ++n)
        acc[4+m][n] = __builtin_amdgcn_mfma_f32_16x16x32_bf16(a[m], b1[n], acc[4+m][n], 0, 0, 0);
    __builtin_amdgcn_s_setprio(0);

    bufR ^= 65536u; bufW ^= 65536u;
    if (t < 10) {
      #pragma unroll
      for (int s = 0; s < 8; ++s) gsrc[s] += 64;
    }
  }
#undef ZSTORE
#undef ISSUE

  // ---- stats: per-(token, 64-col slice) max_l from acc (bf16, nontemporal) --
  #pragma unroll
  for (int m = 0; m < 8; ++m)
    #pragma unroll
    for (int r = 0; r < 4; ++r) {
      float mx = fmaxf(fmaxf(acc[m][0][r], acc[m][1][r]),
                       fmaxf(acc[m][2][r], acc[m][3][r]));
      mx = fmaxf(mx, __shfl_xor(mx, 1));
      mx = fmaxf(mx, __shfl_xor(mx, 2));
      mx = fmaxf(mx, __shfl_xor(mx, 4));
      mx = fmaxf(mx, __shfl_xor(mx, 8));
      if (fr == 0) {
        const int tok = bm0 + wr*128 + m*16 + fq*4 + r;
        __builtin_nontemporal_store(f2bf(mx),
            &statsb[(size_t)tok * 3072 + (bn0 >> 6) + wc]);
      }
    }

  // ---- coalesced C-write via LDS transpose (r10-verified) -------------------
  unsigned short* tb16 = (unsigned short*)lds;
  #pragma unroll
  for (int h = 0; h < 2; ++h) {
    __syncthreads();                     // also drains zero/stat stores
    if (wr == h) {
      #pragma unroll
      for (int m = 0; m < 8; ++m)
        #pragma unroll
        for (int n = 0; n < 4; ++n)
          #pragma unroll
          for (int r = 0; r < 4; ++r)
            tb16[(m*16 + fq*4 + r)*264 + (wc*64 + n*16 + fr)] = f2bf(acc[m][n][r]);
    }
    __syncthreads();
    #pragma unroll
    for (int i = 0; i < 8; ++i) {
      const int n = i*512 + tid;
      const int row = n >> 5, seg = n & 31;
      *(u16x8*)&stash[(size_t)(bm0 + h*128 + row) * 32768 + bn0 + seg*8] =
          *(const u16x8*)&tb16[row*264 + seg*8];
    }
  }
}

// ---------------- K2: pruned select (UB = max_l + max_g per 64-col slice) ----
#define MARGIN 0.125f

__global__ __launch_bounds__(256) void k_select(const unsigned short* stash,    // aliases out_ind
                                                const unsigned short* statsb,   // aliases out_emb
                                                const float* __restrict__ gumbel,
                                                const float* __restrict__ x,
                                                const float* __restrict__ w,
                                                const float* __restrict__ emb_tab,
                                                float* out_emb,
                                                float* out_ind){
  const int t   = blockIdx.x;
  const int tid = threadIdx.x;
  const int lane = tid & 63, wid = tid >> 6;

  __shared__ float gm[128];              // per-slice gumbel max
  __shared__ unsigned short sml[128];    // per-slice logit max (bf16)
  __shared__ float wred[4];
  __shared__ int   wredi[4];
  __shared__ int   bslice;
  __shared__ float lbv;
  __shared__ int   Vint;
  __shared__ int   slist[128];
  __shared__ int   scnt;
  __shared__ int   cand_k[16];
  __shared__ float cand_g[16];
  __shared__ int   cand_cnt;
  __shared__ int   sel_idx[NSc];

  if (tid < 64)
    ((unsigned int*)sml)[tid] = ((const unsigned int*)(statsb + (size_t)t*3072))[tid];
  const unsigned short* srow = stash + (size_t)t * 32768;
  __syncthreads();

  for (int s = 0; s < NSc; ++s) {
    const float* grow = gumbel + ((size_t)t * NSc + s) * Kc;
    if (tid == 0) { scnt = 0; cand_cnt = 0; }

    // pass 1: stream gumbel (only full-row read), per-64-col-slice max
    #pragma unroll
    for (int j = 0; j < 8; ++j) {
      const float4 g4 = ((const float4*)grow)[j*256 + tid];
      float m4 = fmaxf(fmaxf(g4.x, g4.y), fmaxf(g4.z, g4.w));
      m4 = fmaxf(m4, __shfl_xor(m4, 1));
      m4 = fmaxf(m4, __shfl_xor(m4, 2));
      m4 = fmaxf(m4, __shfl_xor(m4, 4));
      m4 = fmaxf(m4, __shfl_xor(m4, 8));
      if ((tid & 15) == 0) gm[j*16 + (tid >> 4)] = m4;
    }
    __syncthreads();

    // argmax-UB slice (tie -> min index)
    float ub = -1e30f; int si = 0;
    if (tid < 128) { ub = gm[tid] + bf2f(sml[tid]); si = tid; }
    #pragma unroll
    for (int off = 1; off < 64; off <<= 1) {
      const float ov = __shfl_xor(ub, off); const int oi = __shfl_xor(si, off);
      if (ov > ub || (ov == ub && oi < si)) { ub = ov; si = oi; }
    }
    if (lane == 0) { wred[wid] = ub; wredi[wid] = si; }
    __syncthreads();
    if (tid == 0) {
      float b = wred[0]; int bi = wredi[0];
      #pragma unroll
      for (int q = 1; q < 4; ++q)
        if (wred[q] > b || (wred[q] == b && wredi[q] < bi)) { b = wred[q]; bi = wredi[q]; }
      bslice = bi;
    }
    __syncthreads();

    // exact LB from best-UB slice (wave 0)
    if (wid == 0) {
      const int k = bslice*64 + lane;
      float v = bf2f(srow[k]) + grow[k];
      #pragma unroll
      for (int off = 1; off < 64; off <<= 1) v = fmaxf(v, __shfl_xor(v, off));
      if (lane == 0) { lbv = v; Vint = __float_as_int(v); }
    }
    __syncthreads();

    // suspects: UB >= LB - MARGIN - slack (0.05 > worst-case bf16 slack 0.032)
    if (tid < 128) {
      if (gm[tid] + bf2f(sml[tid]) >= lbv - MARGIN - 0.05f)
        slist[atomicAdd(&scnt, 1)] = tid;
    }
    __syncthreads();
    const int sc = scnt;

    // exact max V over suspect slices (V = true global max of v')
    for (int i = wid; i < sc; i += 4) {
      const int k = slist[i]*64 + lane;
      float v = bf2f(srow[k]) + grow[k];
      #pragma unroll
      for (int off = 1; off < 64; off <<= 1) v = fmaxf(v, __shfl_xor(v, off));
      if (lane == 0) atomicMax(&Vint, __float_as_int(v));
    }
    __syncthreads();
    const float V = __int_as_float(Vint);

    // candidates within MARGIN of V
    for (int i = wid; i < sc; i += 4) {
      const int k = slist[i]*64 + lane;
      const float v = bf2f(srow[k]) + grow[k];
      if (v >= V - MARGIN) {
        const int p = atomicAdd(&cand_cnt, 1);
        if (p < 16) cand_k[p] = k;
      }
    }
    __syncthreads();

    const int cnt = min(cand_cnt, 16);
    if (cnt == 1) {
      if (tid == 0) sel_idx[s] = cand_k[0];
    } else {
      // exact refine (r1-validated): wave wid takes candidates wid, wid+4, ...
      for (int c = wid; c < cnt; c += 4) {
        const int kc = cand_k[c];
        const float* wr = w + (size_t)kc * Dc;
        const float* xr = x + (size_t)t * Dc;
        double accd = 0.0;
        for (int d = lane; d < Dc; d += 64) accd += (double)xr[d] * (double)wr[d];
        #pragma unroll
        for (int off = 32; off; off >>= 1) accd += __shfl_xor(accd, off);
        if (lane == 0) cand_g[c] = (float)accd + grow[kc];
      }
      __syncthreads();
      if (tid == 0) {
        float bg = -1e30f; int bk = Kc;
        for (int c = 0; c < cnt; ++c) {
          const float gg = cand_g[c]; const int kk = cand_k[c];
          if (gg > bg || (gg == bg && kk < bk)) { bg = gg; bk = kk; }
        }
        sel_idx[s] = bk;
      }
    }
    __syncthreads();
  }

  // ---- lean writes: zero the stash quadrant [t][0][k<4096), then the 1.0s.
  {
    float* row0lo = out_ind + (size_t)t * 16384;
    const float4 z = {0.f, 0.f, 0.f, 0.f};
    #pragma unroll
    for (int q = 0; q < 4; ++q)
      ((float4*)row0lo)[q*256 + tid] = z;
  }
  __syncthreads();
  if (tid == 0) {
    out_ind[(size_t)t*16384 +        sel_idx[0]] = 1.0f;
    out_ind[(size_t)t*16384 + 8192 + sel_idx[1]] = 1.0f;
  }

  // embedding gathers (overwrites the stats bytes of this token's emb rows)
  #pragma unroll
  for (int s = 0; s < NSc; ++s) {
    const float* er = emb_tab + (size_t)sel_idx[s] * Dc;
    float* eo = out_emb + ((size_t)t*NSc + s)*Dc;
    for (int d = tid; d < Dc; d += 256) eo[d] = er[d];
  }
}

extern "C" void kernel_launch(void* const* d_in, const int* in_sizes, int n_in,
                              void* d_out, int out_size, void* d_ws, size_t ws_size,
                              hipStream_t stream) {
  const float* x   = (const float*)d_in[0];
  const float* w   = (const float*)d_in[1];
  const float* emb = (const float*)d_in[2];
  const float* gum = (const float*)d_in[3];

  float* out_emb = (float*)d_out;
  float* out_ind = out_emb + EMB_ELEMS;
  unsigned short* stash  = (unsigned short*)out_ind;   // bf16 row t at ushort t*32768
  unsigned short* statsb = (unsigned short*)out_emb;   // 256 B at token row start

  unsigned short* xb = (unsigned short*)d_ws;           // [M][D] bf16 (12.6 MB)
  unsigned short* wb = xb + (size_t)Mc * Dc;            // [K][D] bf16 (12.6 MB)

  const int n4 = (Mc * Dc) / 4;
  k_convert<<<n4 / 256, 256, 0, stream>>>((const float4*)x, (const float4*)w,
                                          (u16x4*)xb, (u16x4*)wb);
  k_gemm<<<1024, 512, 0, stream>>>(xb, wb, stash, statsb);
  k_select<<<Mc, 256, 0, stream>>>(stash, statsb, gum, x, w, emb, out_emb, out_ind);
}

// Round 15
// 331.948 us; speedup vs baseline: 1.1775x; 1.1775x over previous
//
#include <hip/hip_runtime.h>
#include <stdint.h>

// Problem constants (fixed by the reference)
#define Bc 4
#define Sc 2048
#define Dc 768
#define Kc 8192
#define NSc 2
#define Mc (Bc*Sc)                      // 8192 tokens
#define EMB_ELEMS ((size_t)Mc*NSc*Dc)   // emb output floats; indices follow

typedef __attribute__((ext_vector_type(8))) __bf16 bf16x8;
typedef __attribute__((ext_vector_type(4))) float f32x4;
typedef __attribute__((ext_vector_type(4))) unsigned short u16x4;
typedef __attribute__((ext_vector_type(8))) unsigned short u16x8;

__device__ __forceinline__ unsigned short f2bf(float f){
  unsigned int u = __float_as_uint(f);
  u += 0x7FFFu + ((u >> 16) & 1u);       // round-to-nearest-even
  return (unsigned short)(u >> 16);
}
__device__ __forceinline__ float bf2f(unsigned short h){
  return __uint_as_float(((unsigned int)h) << 16);
}

// ---------------- K0: convert x,w f32 -> bf16 (into ws) ----------------
__global__ __launch_bounds__(256) void k_convert(const float4* __restrict__ x,
                                                 const float4* __restrict__ w,
                                                 u16x4* __restrict__ xb,
                                                 u16x4* __restrict__ wb){
  int i = blockIdx.x * 256 + threadIdx.x;
  float4 v = x[i];
  u16x4 o;
  o.x = f2bf(v.x); o.y = f2bf(v.y); o.z = f2bf(v.z); o.w = f2bf(v.w);
  xb[i] = o;
  v = w[i];
  o.x = f2bf(v.x); o.y = f2bf(v.y); o.z = f2bf(v.z); o.w = f2bf(v.w);
  wb[i] = o;
}

// ---------------- K1: 256x256 4-phase bf16 MFMA GEMM + in-loop zero stores ---
// r13 exactly (measured best, 332 us). Counted-vmcnt ledger:
//   ph0: t==0 -> vmcnt(2), else vmcnt(6)   (newest = Z1(2)+A1,A3+Z2(2))
//   ph1: t==0 -> vmcnt(2), t<11 -> vmcnt(4) (newest = Z2(2)+B0,B1), tail vmcnt(0)
#define BM 128
#define BN 128
#define BK 32

__global__ __launch_bounds__(512, 2) void k_gemm(const unsigned short* __restrict__ xb,
                                                 const unsigned short* __restrict__ wb,
                                                 unsigned short* stash){
  __shared__ __align__(16) unsigned char lds[131072];   // 2 x (A 32K | B 32K)

  const int tid  = threadIdx.x;
  const int lane = tid & 63;
  const int wid  = tid >> 6;             // 8 waves
  const int wr   = wid >> 2;             // M half (0..1)
  const int wc   = wid & 3;              // N quarter (0..3)
  const int fr   = lane & 15;
  const int fq   = lane >> 4;

  // column-ownership XCD swizzle (r12, bijective)
  const int bid = (int)blockIdx.x;
  const int xcd = bid & 7;
  const int ii  = bid >> 3;              // 0..127
  const int bm0 = (ii >> 2) * 256;       // row 0..31 (advances per round)
  const int bn0 = (xcd * 4 + (ii & 3)) * 256;   // col: 4 panels owned per XCD

  float* zbase = (float*)stash;          // out_ind base (row t = 16384 floats)
  const int zpan = bn0 >> 8;             // 0..31: this block's zero partition

  f32x4 acc[8][4] = {};

  const int rin   = tid >> 3;                 // row within unit (0..63)
  const int kblkp = (tid & 7) ^ (rin & 7);    // inverse-swizzled k-block
  const unsigned short* gsrc[8];
  unsigned dstoff[8];
  #pragma unroll
  for (int s = 0; s < 8; ++s) {
    const int isA = s >> 2;
    const int q   = s & 3;
    const int r64 = isA ? (((q & 1) << 1) | (q >> 1)) : q;   // A order 0,2,1,3
    const int grow = (isA ? bm0 : bn0) + r64 * 64 + rin;
    gsrc[s]   = (isA ? xb : wb) + (size_t)grow * Dc + kblkp * 8;
    dstoff[s] = (isA ? 0u : 32768u) + (unsigned)r64 * 8192u + (unsigned)wid * 1024u;
  }

#define ISSUE(s_, bo_) __builtin_amdgcn_global_load_lds( \
    (const __attribute__((address_space(1))) void*)gsrc[s_], \
    (__attribute__((address_space(3))) void*)&lds[(bo_) + dstoff[s_]], 16, 0, 0)

#define ZSTORE(u_) do { \
    const unsigned g_ = (unsigned)(t*4 + (u_))*512u + (unsigned)tid; \
    const unsigned tl_ = g_ / 96u, j4_ = g_ - tl_*96u; \
    const f32x4 z_ = {0.f, 0.f, 0.f, 0.f}; \
    __builtin_nontemporal_store(z_, (f32x4*)(zbase + \
        (size_t)(bm0 + tl_)*16384 + 4096 + zpan*384 + j4_*4)); \
  } while (0)

  // prologue: tile 0 -> buf0
  #pragma unroll
  for (int s = 0; s < 8; ++s) ISSUE(s, 0u);
  #pragma unroll
  for (int s = 0; s < 8; ++s) gsrc[s] += 64;             // point at tile 1

  unsigned bufR = 0u, bufW = 65536u;
  const unsigned aRow = (unsigned)(wr*128 + fr) * 128u;            // A row byte
  const unsigned bRow = (unsigned)(wc*64  + fr) * 128u + 32768u;   // B row byte
  const unsigned sl0  = (unsigned)((fq       ) ^ (fr & 7)) * 16u;  // k-step 0 slot
  const unsigned sl1  = (unsigned)((fq + 4   ) ^ (fr & 7)) * 16u;  // k-step 1 slot

  for (int t = 0; t < 12; ++t) {
    const bool more = (t < 11);
    bf16x8 a[4], b0[4], b1[4];

    // ---------------- ph0: k-step 0, m-half 0 ----------------
    if (t == 0) asm volatile("s_waitcnt vmcnt(2)" ::: "memory");
    else        asm volatile("s_waitcnt vmcnt(6)" ::: "memory");
    __builtin_amdgcn_s_barrier();
    asm volatile("" ::: "memory");
    if (more) { ISSUE(0, bufW); ISSUE(1, bufW); }
    #pragma unroll
    for (int n = 0; n < 4; ++n) b0[n] = *(const bf16x8*)&lds[bufR + bRow + (unsigned)n*2048u + sl0];
    #pragma unroll
    for (int m = 0; m < 4; ++m) a[m]  = *(const bf16x8*)&lds[bufR + aRow + (unsigned)m*2048u + sl0];
    __builtin_amdgcn_s_setprio(1);
    #pragma unroll
    for (int m = 0; m < 4; ++m)
      #pragma unroll
      for (int n = 0; n < 4; ++n)
        acc[m][n] = __builtin_amdgcn_mfma_f32_16x16x32_bf16(a[m], b0[n], acc[m][n], 0, 0, 0);
    __builtin_amdgcn_s_setprio(0);

    // ---------------- ph1: k-step 0, m-half 1 ----------------
    if (!more)       asm volatile("s_waitcnt vmcnt(0)" ::: "memory");
    else if (t == 0) asm volatile("s_waitcnt vmcnt(2)" ::: "memory");
    else             asm volatile("s_waitcnt vmcnt(4)" ::: "memory");
    __builtin_amdgcn_s_barrier();
    asm volatile("" ::: "memory");
    if (more) { ISSUE(2, bufW); ISSUE(3, bufW); }
    #pragma unroll
    for (int m = 0; m < 4; ++m) a[m] = *(const bf16x8*)&lds[bufR + aRow + 8192u + (unsigned)m*2048u + sl0];
    __builtin_amdgcn_s_setprio(1);
    #pragma unroll
    for (int m = 0; m < 4; ++m)
      #pragma unroll
      for (int n = 0; n < 4; ++n)
        acc[4+m][n] = __builtin_amdgcn_mfma_f32_16x16x32_bf16(a[m], b0[n], acc[4+m][n], 0, 0, 0);
    __builtin_amdgcn_s_setprio(0);

    // ---------------- ph2: k-step 1, m-half 0 (waitless) ----------------
    if (more) { ISSUE(4, bufW); ISSUE(5, bufW); }
    asm volatile("" ::: "memory");
    ZSTORE(0); ZSTORE(1);
    asm volatile("" ::: "memory");
    #pragma unroll
    for (int n = 0; n < 4; ++n) b1[n] = *(const bf16x8*)&lds[bufR + bRow + (unsigned)n*2048u + sl1];
    #pragma unroll
    for (int m = 0; m < 4; ++m) a[m]  = *(const bf16x8*)&lds[bufR + aRow + (unsigned)m*2048u + sl1];
    __builtin_amdgcn_s_setprio(1);
    #pragma unroll
    for (int m = 0; m < 4; ++m)
      #pragma unroll
      for (int n = 0; n < 4; ++n)
        acc[m][n] = __builtin_amdgcn_mfma_f32_16x16x32_bf16(a[m], b1[n], acc[m][n], 0, 0, 0);
    __builtin_amdgcn_s_setprio(0);

    // ---------------- ph3: k-step 1, m-half 1 (waitless) ----------------
    if (more) { ISSUE(6, bufW); ISSUE(7, bufW); }
    asm volatile("" ::: "memory");
    ZSTORE(2); ZSTORE(3);
    asm volatile("" ::: "memory");
    #pragma unroll
    for (int m = 0; m < 4; ++m) a[m] = *(const bf16x8*)&lds[bufR + aRow + 8192u + (unsigned)m*2048u + sl1];
    __builtin_amdgcn_s_setprio(1);
    #pragma unroll
    for (int m = 0; m < 4; ++m)
      #pragma unroll
      for (int n = 0; n < 4; ++n)
        acc[4+m][n] = __builtin_amdgcn_mfma_f32_16x16x32_bf16(a[m], b1[n], acc[4+m][n], 0, 0, 0);
    __builtin_amdgcn_s_setprio(0);

    bufR ^= 65536u; bufW ^= 65536u;
    if (t < 10) {
      #pragma unroll
      for (int s = 0; s < 8; ++s) gsrc[s] += 64;
    }
  }
#undef ZSTORE
#undef ISSUE

  // ---- coalesced C-write via LDS transpose (r10-verified) -------------------
  // C/D layout: col = lane&15, row = (lane>>4)*4 + reg (validated r1..r13).
  unsigned short* tb16 = (unsigned short*)lds;
  #pragma unroll
  for (int h = 0; h < 2; ++h) {
    __syncthreads();                     // also drains remaining zero stores
    if (wr == h) {
      #pragma unroll
      for (int m = 0; m < 8; ++m)
        #pragma unroll
        for (int n = 0; n < 4; ++n)
          #pragma unroll
          for (int r = 0; r < 4; ++r)
            tb16[(m*16 + fq*4 + r)*264 + (wc*64 + n*16 + fr)] = f2bf(acc[m][n][r]);
    }
    __syncthreads();
    #pragma unroll
    for (int i = 0; i < 8; ++i) {
      const int n = i*512 + tid;
      const int row = n >> 5, seg = n & 31;
      *(u16x8*)&stash[(size_t)(bm0 + h*128 + row) * 32768 + bn0 + seg*8] =
          *(const u16x8*)&tb16[row*264 + seg*8];
    }
  }
}

// ---------------- K2: lean select (r1 logic; writes only stash quadrant) -----
#define MARGIN 0.125f

__global__ __launch_bounds__(256) void k_select(const unsigned short* logits,   // aliases out_ind!
                                                const float* __restrict__ gumbel,
                                                const float* __restrict__ x,
                                                const float* __restrict__ w,
                                                const float* __restrict__ emb_tab,
                                                float* __restrict__ out_emb,
                                                float* out_ind){
  const int t   = blockIdx.x;
  const int tid = threadIdx.x;
  const int lane = tid & 63, wid = tid >> 6;

  __shared__ unsigned short Lrow[Kc];    // 16 KB bf16 logits row
  __shared__ float wmax[4];
  __shared__ int   cand_k[16];
  __shared__ float cand_g[16];
  __shared__ int   cand_cnt;
  __shared__ int   sel_idx[NSc];

  // stage logits row t into LDS (stash quadrant [t][0][k<4096] overwritten below)
  {
    const u16x4* src = (const u16x4*)(logits + (size_t)t * 32768);
    u16x4* dst = (u16x4*)Lrow;
    #pragma unroll
    for (int j = 0; j < 8; j++) dst[j*256 + tid] = src[j*256 + tid];
  }
  __syncthreads();

  for (int s = 0; s < NSc; ++s) {
    const float* grow = gumbel + ((size_t)t * NSc + s) * Kc;
    float4 vals[8];
    float m = -1e30f;
    #pragma unroll
    for (int j = 0; j < 8; j++) {
      float4 g4 = ((const float4*)grow)[j*256 + tid];
      u16x4 l4 = *(const u16x4*)&Lrow[j*1024 + tid*4];
      float4 v;
      v.x = bf2f(l4.x) + g4.x;
      v.y = bf2f(l4.y) + g4.y;
      v.z = bf2f(l4.z) + g4.z;
      v.w = bf2f(l4.w) + g4.w;
      vals[j] = v;
      m = fmaxf(m, fmaxf(fmaxf(v.x, v.y), fmaxf(v.z, v.w)));
    }
    #pragma unroll
    for (int off = 32; off; off >>= 1) m = fmaxf(m, __shfl_xor(m, off));
    if (lane == 0) wmax[wid] = m;
    __syncthreads();
    const float gmax = fmaxf(fmaxf(wmax[0], wmax[1]), fmaxf(wmax[2], wmax[3]));
    if (tid == 0) cand_cnt = 0;
    __syncthreads();

    const float thr = gmax - MARGIN;
    #pragma unroll
    for (int j = 0; j < 8; j++) {
      const int k0 = j*1024 + tid*4;
      float vv[4] = {vals[j].x, vals[j].y, vals[j].z, vals[j].w};
      #pragma unroll
      for (int q = 0; q < 4; q++) {
        if (vv[q] >= thr) {
          int p = atomicAdd(&cand_cnt, 1);
          if (p < 16) cand_k[p] = k0 + q;
        }
      }
    }
    __syncthreads();

    const int cnt = min(cand_cnt, 16);
    if (cnt == 1) {
      if (tid == 0) sel_idx[s] = cand_k[0];
    } else {
      // exact refine: wave `wid` takes candidates wid, wid+4, ...
      for (int c = wid; c < cnt; c += 4) {
        const int kc = cand_k[c];
        const float* wr = w + (size_t)kc * Dc;
        const float* xr = x + (size_t)t * Dc;
        double accd = 0.0;
        for (int d = lane; d < Dc; d += 64) accd += (double)xr[d] * (double)wr[d];
        #pragma unroll
        for (int off = 32; off; off >>= 1) accd += __shfl_xor(accd, off);
        if (lane == 0) cand_g[c] = (float)accd + grow[kc];  // f32 add, like ref
      }
      __syncthreads();
      if (tid == 0) {
        float bg = -1e30f; int bk_ = Kc;
        for (int c = 0; c < cnt; c++) {
          float g = cand_g[c]; int kk = cand_k[c];
          if (g > bg || (g == bg && kk < bk_)) { bg = g; bk_ = kk; }
        }
        sel_idx[s] = bk_;
      }
    }
    __syncthreads();
  }

  // ---- lean writes: zero ONLY the stash quadrant [t][0][k<4096); everything
  // else was pre-zeroed by k_gemm. Then the two 1.0s, then emb gathers.
  {
    float* row0lo = out_ind + (size_t)t * 16384;
    const float4 z = {0.f, 0.f, 0.f, 0.f};
    #pragma unroll
    for (int q = 0; q < 4; ++q)
      ((float4*)row0lo)[q*256 + tid] = z;
  }
  __syncthreads();                        // zeros land before the 1.0s
  if (tid == 0) {
    out_ind[(size_t)t*16384 +        sel_idx[0]] = 1.0f;
    out_ind[(size_t)t*16384 + 8192 + sel_idx[1]] = 1.0f;
  }

  #pragma unroll
  for (int s = 0; s < NSc; ++s) {
    const float* er = emb_tab + (size_t)sel_idx[s] * Dc;
    float* eo = out_emb + ((size_t)t*NSc + s)*Dc;
    for (int d = tid; d < Dc; d += 256) eo[d] = er[d];
  }
}

extern "C" void kernel_launch(void* const* d_in, const int* in_sizes, int n_in,
                              void* d_out, int out_size, void* d_ws, size_t ws_size,
                              hipStream_t stream) {
  const float* x   = (const float*)d_in[0];
  const float* w   = (const float*)d_in[1];
  const float* emb = (const float*)d_in[2];
  const float* gum = (const float*)d_in[3];

  float* out_emb = (float*)d_out;
  float* out_ind = out_emb + EMB_ELEMS;
  // bf16 logits staged inside the indices region: token row t at ushort t*32768
  unsigned short* stash = (unsigned short*)out_ind;

  unsigned short* xb = (unsigned short*)d_ws;           // [M][D] bf16 (12.6 MB)
  unsigned short* wb = xb + (size_t)Mc * Dc;            // [K][D] bf16 (12.6 MB)

  const int n4 = (Mc * Dc) / 4;
  k_convert<<<n4 / 256, 256, 0, stream>>>((const float4*)x, (const float4*)w,
                                          (u16x4*)xb, (u16x4*)wb);
  k_gemm<<<1024, 512, 0, stream>>>(xb, wb, stash);
  k_select<<<Mc, 256, 0, stream>>>(stash, gum, x, w, emb, out_emb, out_ind);
}